// Round 4
// baseline (277.736 us; speedup 1.0000x reference)
//
#include <hip/hip_runtime.h>
#include <cstdint>
#include <cstddef>

// Problem sizes (fixed by the reference)
#define MDIM 16384   // N_INPUT
#define CDIM 4096    // NUM_CENTERS
#define DDIM 256     // DIM
#define KDIM 512     // folded K elements; fp4 -> 256 bytes per row
#define KB   256     // row bytes (fp4)

typedef float f32x4  __attribute__((ext_vector_type(4)));
typedef int   i32x4v __attribute__((ext_vector_type(4)));
typedef int   i32x8v __attribute__((ext_vector_type(8)));

// e2m1 (OCP MXFP4) quantize, round-to-nearest: grid {0,.5,1,1.5,2,3,4,6}
__device__ __forceinline__ unsigned q4(float v) {
    unsigned s = (__builtin_bit_cast(unsigned, v) >> 31) << 3;
    float a = fabsf(v);
    unsigned c = (unsigned)(a >= 0.25f) + (a >= 0.75f) + (a >= 1.25f)
               + (a >= 1.75f) + (a >= 2.5f) + (a >= 3.5f) + (a >= 5.0f);
    return s | c;
}
__device__ __forceinline__ unsigned pack8(const float* v) {  // 8 vals -> 8 nibbles
    unsigned w = 0;
    #pragma unroll
    for (int i = 0; i < 8; ++i) w |= q4(v[i]) << (4 * i);
    return w;
}

// ---------------------------------------------------------------------------
// prep (fp4): A'[n] = [ x (256 fp4) | x^2/8 (256 fp4) ]       row = 256 B
//             B'[c] = [ -2*c*inv (256 fp4) | inv*8 (256 fp4) ]
//             constc[c] = sum_d c^2*inv (fp32).  Scales undone by MFMA E8M0.
//             Also zeroes score[] and the 64 bg-completion counters.
// ---------------------------------------------------------------------------
__global__ __launch_bounds__(256) void prep(
    const float* __restrict__ x, const float* __restrict__ centers,
    const float* __restrict__ sigmas,
    unsigned char* __restrict__ Ap, unsigned char* __restrict__ Bp,
    float* __restrict__ constc, float* __restrict__ score,
    int* __restrict__ cnt) {
    int b = blockIdx.x, tid = threadIdx.x;
    if (b < 2048) {
        int idx8 = b * 256 + tid;                 // over MDIM*DDIM/8
        int n = idx8 >> 5, d8 = idx8 & 31;
        float v[8], v2[8];
        *(float4*)(v)     = ((const float4*)x)[idx8 * 2];
        *(float4*)(v + 4) = ((const float4*)x)[idx8 * 2 + 1];
        #pragma unroll
        for (int i = 0; i < 8; ++i) v2[i] = v[i] * v[i] * 0.125f;  // x^2/8
        *(unsigned*)(Ap + (size_t)n * KB + d8 * 4)       = pack8(v);
        *(unsigned*)(Ap + (size_t)n * KB + 128 + d8 * 4) = pack8(v2);
        if (idx8 < MDIM) score[idx8] = 0.0f;
        if (b == 0 && tid < 64) cnt[tid] = 0;
    } else {
        int gid8 = (b - 2048) * 256 + tid;        // over CDIM*DDIM/8
        int c = gid8 >> 5, d8 = gid8 & 31;
        float cv[8], sv[8], cr[8], iv[8];
        *(float4*)(cv)     = ((const float4*)centers)[gid8 * 2];
        *(float4*)(cv + 4) = ((const float4*)centers)[gid8 * 2 + 1];
        *(float4*)(sv)     = ((const float4*)sigmas)[gid8 * 2];
        *(float4*)(sv + 4) = ((const float4*)sigmas)[gid8 * 2 + 1];
        float t = 0.0f;
        #pragma unroll
        for (int i = 0; i < 8; ++i) {
            float inv = 1.0f / (2.0f * sv[i] * sv[i]);
            cr[i] = -2.0f * cv[i] * inv;
            iv[i] = inv * 8.0f;                   // inv*8 (undone by 2^-3)
            t += cv[i] * cv[i] * inv;
        }
        *(unsigned*)(Bp + (size_t)c * KB + d8 * 4)       = pack8(cr);
        *(unsigned*)(Bp + (size_t)c * KB + 128 + d8 * 4) = pack8(iv);
        #pragma unroll
        for (int m = 16; m; m >>= 1) t += __shfl_xor(t, m, 64);  // 32-lane groups
        if ((tid & 31) == 0) constc[c] = t;
    }
}

// ---------------------------------------------------------------------------
// Fused MX-fp4 GEMM + exp + weighted C-reduction + final sigmoid.  (R18)
// d2 = A' B'^T + constc ; score[m] += sum_n exp(-d2[m][n]) * w[n]
//
// R18 (post-mortems R16/R17): R16's single-barrier structure was best
// (45 µs, occ 34%); R17's 8-tile persistence killed TLP (2 blocks/CU,
// MfmaUtil 8.6%, +15 µs).  This version:
//   * 2 M-tiles per block, grid 32(bn) x 64(bg) = 2048 blocks (8/CU
//     pipelined).  B staged ONCE per block (half of R16's staging work
//     per tile), ONE barrier; tile-1 A-loads issued right after the
//     barrier so their L2 latency hides under tile-0's 64 MFMAs.
//   * A direct global->VGPR (wave-private; L2/L3-served; no LDS).
//   * finalize FUSED: per-bg completion counter; the 32nd (bn) block to
//     finish rows [bg*256,+256) applies sigmoid+bias and writes out[].
//     Device-scope atomics + threadfence; score read back via
//     atomicAdd(p, 0.0f) to bypass stale L1.
//   * LDS: two [128][128] stride-128 buffers (R12/R17 pattern, measured
//     0 conflicts; R16's 256B-stride variant measured 2^21 cycles).
// ---------------------------------------------------------------------------
#define AS1 __attribute__((address_space(1)))
#define AS3 __attribute__((address_space(3)))

__global__ __launch_bounds__(256, 3) void gemm_fused(
    const unsigned char* __restrict__ A, const unsigned char* __restrict__ B,
    const float* __restrict__ constc, const float* __restrict__ w,
    float* __restrict__ score, const float* __restrict__ b_lin,
    float* __restrict__ out, int* __restrict__ cnt) {

    __shared__ unsigned char Bs0[128 * 128];   // K-half 0 (bytes 0..127)
    __shared__ unsigned char Bs1[128 * 128];   // K-half 1 (bytes 128..255)

    const int tid  = threadIdx.x;
    const int wave = tid >> 6;
    const int lane = tid & 63;
    const int quad = lane >> 4;      // 0..3
    const int l16  = lane & 15;

    const int bn = blockIdx.x;       // 0..31  (C blocks of 128)
    const int bg = blockIdx.y;       // 0..63  (groups of 2 M-tiles = 256 rows)

    const int wave_m = wave * 32;    // wave's 32 M-rows within a tile

    // ---- stage B once (R12/R17 pattern, 0 conflicts): slab = 8 rows x 128 B;
    // lane -> row (lane>>3), chunk (lane&7); source pre-swizzled chunk^row.
    const unsigned char* Bbase = B + (size_t)(bn * 128) * KB;
    {
        const int st_row = lane >> 3;                  // 0..7
        const int st_k   = ((lane & 7) ^ st_row) * 16; // swizzled byte off
        #pragma unroll
        for (int c = 0; c < 4; ++c) {
            int slab = wave * 4 + c;                   // 0..15
            const unsigned char* g0 = Bbase + (size_t)(slab * 8 + st_row) * KB + st_k;
            __builtin_amdgcn_global_load_lds((const AS1 void*)g0,
                (AS3 void*)(Bs0 + slab * 1024), 16, 0, 0);
            const unsigned char* g1 = Bbase + (size_t)(slab * 8 + st_row) * KB + 128 + st_k;
            __builtin_amdgcn_global_load_lds((const AS1 void*)g1,
                (AS3 void*)(Bs1 + slab * 1024), 16, 0, 0);
        }
    }

    // ---- epilogue constants: bn-dependent only, loaded once.
    const float NEG_LOG2E = -1.4426950408889634f;
    float wj[8], cjl[8];
    #pragma unroll
    for (int j = 0; j < 8; ++j) {
        int ng = bn * 128 + j * 16 + l16;
        wj[j]  = w[ng];
        cjl[j] = NEG_LOG2E * constc[ng];
    }

    // ---- A fragments, tile 0, direct global->VGPR.
    // row = bg*256 + t*128 + wave_m + i*16 + l16; byte = kh*64 + quad*16.
    const unsigned char* Arow = A + (size_t)(bg * 256 + wave_m + l16) * KB + quad * 16;

    i32x4v afA[2][4], afB[2][4];
    #pragma unroll
    for (int i = 0; i < 2; ++i)
        #pragma unroll
        for (int kh = 0; kh < 4; ++kh)
            afA[i][kh] = *(const i32x4v*)(Arow + (size_t)(i * 16) * KB + kh * 64);

    __syncthreads();   // single barrier: B staged; afA + constants landed

    // ---- issue tile-1 A-loads now; latency hides under tile-0 compute.
    #pragma unroll
    for (int i = 0; i < 2; ++i)
        #pragma unroll
        for (int kh = 0; kh < 4; ++kh)
            afB[i][kh] = *(const i32x4v*)(Arow + (size_t)(128 + i * 16) * KB + kh * 64);

    const int rsw = l16 & 7;
    f32x4 acc[2][8];

#define COMPUTE(af, t)                                                         \
    {                                                                          \
        _Pragma("unroll")                                                      \
        for (int i = 0; i < 2; ++i)                                            \
            _Pragma("unroll")                                                  \
            for (int j = 0; j < 8; ++j) acc[i][j] = (f32x4){0.f,0.f,0.f,0.f};  \
        _Pragma("unroll")                                                      \
        for (int kh = 0; kh < 4; ++kh) {                                       \
            const int sA = (kh & 2) ? 0x82828282 : 0x7F7F7F7F;                 \
            const int sB = (kh & 2) ? 0x7C7C7C7C : 0x7F7F7F7F;                 \
            const unsigned char* Bbuf = (kh >> 1) ? Bs1 : Bs0;                 \
            const int sl = ((((kh & 1) * 4 + quad) ^ rsw) * 16);               \
            _Pragma("unroll")                                                  \
            for (int j = 0; j < 8; ++j) {                                      \
                i32x4v lo = *(const i32x4v*)(Bbuf + (j * 16 + l16) * 128 + sl);\
                i32x8v bf = __builtin_shufflevector(lo, lo, 0,1,2,3,-1,-1,-1,-1);\
                _Pragma("unroll")                                              \
                for (int i = 0; i < 2; ++i) {                                  \
                    i32x8v a8 = __builtin_shufflevector(af[i][kh], af[i][kh],  \
                                                        0,1,2,3,-1,-1,-1,-1); \
                    acc[i][j] = __builtin_amdgcn_mfma_scale_f32_16x16x128_f8f6f4(\
                        a8, bf, acc[i][j], 4, 4, 0, sA, 0, sB);                \
                }                                                              \
            }                                                                  \
        }                                                                      \
        float rowsum[2][4];                                                    \
        _Pragma("unroll")                                                      \
        for (int i = 0; i < 2; ++i)                                            \
            _Pragma("unroll")                                                  \
            for (int r = 0; r < 4; ++r) rowsum[i][r] = 0.0f;                   \
        _Pragma("unroll")                                                      \
        for (int j = 0; j < 8; ++j)                                            \
            _Pragma("unroll")                                                  \
            for (int i = 0; i < 2; ++i)                                        \
                _Pragma("unroll")                                              \
                for (int r = 0; r < 4; ++r)                                    \
                    rowsum[i][r] += exp2f(fmaf(acc[i][j][r], NEG_LOG2E, cjl[j])) * wj[j]; \
        _Pragma("unroll")                                                      \
        for (int mask = 1; mask < 16; mask <<= 1)                              \
            _Pragma("unroll")                                                  \
            for (int i = 0; i < 2; ++i)                                        \
                _Pragma("unroll")                                              \
                for (int r = 0; r < 4; ++r)                                    \
                    rowsum[i][r] += __shfl_xor(rowsum[i][r], mask, 64);        \
        if (l16 == 0) {                                                        \
            _Pragma("unroll")                                                  \
            for (int i = 0; i < 2; ++i)                                        \
                _Pragma("unroll")                                              \
                for (int r = 0; r < 4; ++r) {                                  \
                    int mg = bg * 256 + (t) * 128 + wave_m + i * 16 + quad * 4 + r; \
                    atomicAdd(&score[mg], rowsum[i][r]);                       \
                }                                                              \
        }                                                                      \
    }

    COMPUTE(afA, 0);
    COMPUTE(afB, 1);
#undef COMPUTE

    // ---- fused finalize: last (bn) block for this bg applies sigmoid.
    __threadfence();                       // release: score-atomics visible
    __shared__ int done_s;
    if (tid == 0) done_s = atomicAdd(&cnt[bg], 1);
    __syncthreads();
    if (done_s == 31) {
        __threadfence();                   // acquire side
        int n = bg * 256 + tid;            // 256 threads = 256 rows
        float s = atomicAdd(&score[n], 0.0f) + b_lin[0];   // coherent read
        out[n] = 1.0f / (1.0f + exp2f(-1.4426950408889634f * s));
    }
}

extern "C" void kernel_launch(void* const* d_in, const int* in_sizes, int n_in,
                              void* d_out, int out_size, void* d_ws, size_t ws_size,
                              hipStream_t stream) {
    const float* x       = (const float*)d_in[0];
    const float* centers = (const float*)d_in[1];
    const float* sigmas  = (const float*)d_in[2];
    const float* w_lin   = (const float*)d_in[3];
    const float* b_lin   = (const float*)d_in[4];
    float* out = (float*)d_out;

    char* ws = (char*)d_ws;
    unsigned char* Ap = (unsigned char*)ws;                       // 4 MB
    unsigned char* Bp = (unsigned char*)(ws + (size_t)MDIM * KB); // 1 MB
    float* cc    = (float*)(ws + (size_t)MDIM * KB + (size_t)CDIM * KB); // 16 KB
    float* score = (float*)((char*)cc + CDIM * sizeof(float));    // 64 KB
    int*   cnt   = (int*)((char*)score + MDIM * sizeof(float));   // 256 B

    prep<<<dim3(2048 + 512), dim3(256), 0, stream>>>(
        x, centers, sigmas, Ap, Bp, cc, score, cnt);
    gemm_fused<<<dim3(CDIM / 128, MDIM / 256), dim3(256), 0, stream>>>(
        Ap, Bp, cc, w_lin, score, b_lin, out, cnt);
}

// Round 5
// 129.916 us; speedup vs baseline: 2.1378x; 2.1378x over previous
//
#include <hip/hip_runtime.h>
#include <cstdint>
#include <cstddef>

// Problem sizes (fixed by the reference)
#define MDIM 16384   // N_INPUT
#define CDIM 4096    // NUM_CENTERS
#define DDIM 256     // DIM
#define KDIM 512     // folded K elements; fp4 -> 256 bytes per row
#define KB   256     // row bytes (fp4)

typedef float f32x4  __attribute__((ext_vector_type(4)));
typedef int   i32x4v __attribute__((ext_vector_type(4)));
typedef int   i32x8v __attribute__((ext_vector_type(8)));

// e2m1 (OCP MXFP4) quantize, round-to-nearest: grid {0,.5,1,1.5,2,3,4,6}
__device__ __forceinline__ unsigned q4(float v) {
    unsigned s = (__builtin_bit_cast(unsigned, v) >> 31) << 3;
    float a = fabsf(v);
    unsigned c = (unsigned)(a >= 0.25f) + (a >= 0.75f) + (a >= 1.25f)
               + (a >= 1.75f) + (a >= 2.5f) + (a >= 3.5f) + (a >= 5.0f);
    return s | c;
}
__device__ __forceinline__ unsigned pack8(const float* v) {  // 8 vals -> 8 nibbles
    unsigned w = 0;
    #pragma unroll
    for (int i = 0; i < 8; ++i) w |= q4(v[i]) << (4 * i);
    return w;
}

// ---------------------------------------------------------------------------
// prep (fp4): A'[n] = [ x (256 fp4) | x^2/8 (256 fp4) ]       row = 256 B
//             B'[c] = [ -2*c*inv (256 fp4) | inv*8 (256 fp4) ]
//             constc[c] = sum_d c^2*inv (fp32).  Scales undone by MFMA E8M0.
// ---------------------------------------------------------------------------
__global__ __launch_bounds__(256) void prep(
    const float* __restrict__ x, const float* __restrict__ centers,
    const float* __restrict__ sigmas,
    unsigned char* __restrict__ Ap, unsigned char* __restrict__ Bp,
    float* __restrict__ constc, float* __restrict__ score) {
    int b = blockIdx.x, tid = threadIdx.x;
    if (b < 2048) {
        int idx8 = b * 256 + tid;                 // over MDIM*DDIM/8
        int n = idx8 >> 5, d8 = idx8 & 31;
        float v[8], v2[8];
        *(float4*)(v)     = ((const float4*)x)[idx8 * 2];
        *(float4*)(v + 4) = ((const float4*)x)[idx8 * 2 + 1];
        #pragma unroll
        for (int i = 0; i < 8; ++i) v2[i] = v[i] * v[i] * 0.125f;  // x^2/8
        *(unsigned*)(Ap + (size_t)n * KB + d8 * 4)       = pack8(v);
        *(unsigned*)(Ap + (size_t)n * KB + 128 + d8 * 4) = pack8(v2);
        if (idx8 < MDIM) score[idx8] = 0.0f;
    } else {
        int gid8 = (b - 2048) * 256 + tid;        // over CDIM*DDIM/8
        int c = gid8 >> 5, d8 = gid8 & 31;
        float cv[8], sv[8], cr[8], iv[8];
        *(float4*)(cv)     = ((const float4*)centers)[gid8 * 2];
        *(float4*)(cv + 4) = ((const float4*)centers)[gid8 * 2 + 1];
        *(float4*)(sv)     = ((const float4*)sigmas)[gid8 * 2];
        *(float4*)(sv + 4) = ((const float4*)sigmas)[gid8 * 2 + 1];
        float t = 0.0f;
        #pragma unroll
        for (int i = 0; i < 8; ++i) {
            float inv = 1.0f / (2.0f * sv[i] * sv[i]);
            cr[i] = -2.0f * cv[i] * inv;
            iv[i] = inv * 8.0f;                   // inv*8 (undone by 2^-3)
            t += cv[i] * cv[i] * inv;
        }
        *(unsigned*)(Bp + (size_t)c * KB + d8 * 4)       = pack8(cr);
        *(unsigned*)(Bp + (size_t)c * KB + 128 + d8 * 4) = pack8(iv);
        #pragma unroll
        for (int m = 16; m; m >>= 1) t += __shfl_xor(t, m, 64);  // 32-lane groups
        if ((tid & 31) == 0) constc[c] = t;
    }
}

// ---------------------------------------------------------------------------
// Fused MX-fp4 GEMM + exp + weighted C-reduction.  (R19)
// d2 = A' B'^T + constc ; score[m] += sum_n exp(-d2[m][n]) * w[n]
//
// R19 = R16 single-barrier structure (best measured: 45.0 µs, occ 34%,
// VGPR 64) with two fixes from the R16/R18 post-mortems:
//   1. LDS as two stride-128 [128][128] buffers (R12/R17 staging pattern,
//      twice measured 0 bank conflicts).  R16's [128][256] single buffer
//      measured 2^21 conflict cycles.
//   2. XCD-aware block remap.  HW round-robins linear block id over the
//      8 XCDs (xcd = bid%8); with bn in the fast dim, the 32 blocks
//      sharing one A-panel spread over all XCDs and each private L2
//      re-fetches A (FETCH 17 MB for 5 MB of data).  Remap so XCD k owns
//      bm in [k*16,k*16+16) x all bn: per-XCD working set = A 512 KB +
//      B 1 MB = 1.5 MB < 4 MB L2 -> each XCD fetches A/B once (~12 MB
//      total).  Under HBM contention with the harness's concurrent
//      poison fill, gemm time ~ traffic/residual-BW, so less traffic =
//      faster dispatch.
//   R18 lesson (VGPR 76 = acc spilled, 5x slowdown): keep the kernel
//   tail minimal — separate finalize kernel, nothing after the epilogue.
// ---------------------------------------------------------------------------
#define AS1 __attribute__((address_space(1)))
#define AS3 __attribute__((address_space(3)))

__global__ __launch_bounds__(256, 3) void gemm_fused(
    const unsigned char* __restrict__ A, const unsigned char* __restrict__ B,
    const float* __restrict__ constc, const float* __restrict__ w,
    float* __restrict__ score) {

    __shared__ unsigned char Bs0[128 * 128];   // K-half 0 (bytes 0..127)
    __shared__ unsigned char Bs1[128 * 128];   // K-half 1 (bytes 128..255)

    const int tid  = threadIdx.x;
    const int wave = tid >> 6;
    const int lane = tid & 63;
    const int quad = lane >> 4;      // 0..3
    const int l16  = lane & 15;

    // XCD-aware decomposition: xcd = f&7 (HW round-robin), each XCD owns
    // a 16(bm) x 32(bn) rectangle of tiles.
    const int f   = blockIdx.x;          // 0..4095
    const int xcd = f & 7;
    const int wkr = f >> 3;              // 0..511
    const int bn  = wkr & 31;            // 0..31
    const int bm  = xcd * 16 + (wkr >> 5);  // 0..127

    const int wave_m = wave * 32;    // wave's 32 M-rows

    // ---- stage B once (R12/R17 pattern, 0 conflicts): slab = 8 rows x 128 B
    // per buffer; lane -> row (lane>>3), chunk (lane&7); src pre-swizzled ^row.
    const unsigned char* Bbase = B + (size_t)(bn * 128) * KB;
    {
        const int st_row = lane >> 3;                  // 0..7
        const int st_k   = ((lane & 7) ^ st_row) * 16; // swizzled byte off
        #pragma unroll
        for (int c = 0; c < 4; ++c) {
            int slab = wave * 4 + c;                   // 0..15
            const unsigned char* g0 = Bbase + (size_t)(slab * 8 + st_row) * KB + st_k;
            __builtin_amdgcn_global_load_lds((const AS1 void*)g0,
                (AS3 void*)(Bs0 + slab * 1024), 16, 0, 0);
            const unsigned char* g1 = Bbase + (size_t)(slab * 8 + st_row) * KB + 128 + st_k;
            __builtin_amdgcn_global_load_lds((const AS1 void*)g1,
                (AS3 void*)(Bs1 + slab * 1024), 16, 0, 0);
        }
    }

    // ---- A fragments direct global->VGPR (wave-private; L2-served).
    // row = bm*128 + wave_m + i*16 + l16; byte = kh*64 + quad*16.
    const unsigned char* Abase = A + (size_t)(bm * 128 + wave_m) * KB;
    i32x4v af[2][4];
    #pragma unroll
    for (int i = 0; i < 2; ++i)
        #pragma unroll
        for (int kh = 0; kh < 4; ++kh)
            af[i][kh] = *(const i32x4v*)(Abase + (size_t)(i * 16 + l16) * KB
                                         + kh * 64 + quad * 16);

    __syncthreads();   // single drain: B in LDS (all waves), af landed in regs

    f32x4 acc[2][8] = {};
    const int rsw = l16 & 7;
    #pragma unroll
    for (int kh = 0; kh < 4; ++kh) {          // 4 K-windows of 128 elems
        const int sA = (kh & 2) ? 0x82828282 : 0x7F7F7F7F;   // 2^3 : 2^0
        const int sB = (kh & 2) ? 0x7C7C7C7C : 0x7F7F7F7F;   // 2^-3 : 2^0
        const unsigned char* Bbuf = (kh >> 1) ? Bs1 : Bs0;
        const int sl = ((((kh & 1) * 4 + quad) ^ rsw) * 16);
        #pragma unroll
        for (int j = 0; j < 8; ++j) {
            i32x4v lo = *(const i32x4v*)(Bbuf + (j * 16 + l16) * 128 + sl);
            i32x8v bf = __builtin_shufflevector(lo, lo, 0, 1, 2, 3, -1, -1, -1, -1);
            #pragma unroll
            for (int i = 0; i < 2; ++i) {
                i32x8v a8 = __builtin_shufflevector(af[i][kh], af[i][kh],
                                                    0, 1, 2, 3, -1, -1, -1, -1);
                acc[i][j] = __builtin_amdgcn_mfma_scale_f32_16x16x128_f8f6f4(
                    a8, bf, acc[i][j],
                    4 /*cbsz: fp4 e2m1*/, 4 /*blgp: fp4 e2m1*/,
                    0, sA, 0, sB);
            }
        }
    }

    // Epilogue (constants loaded here, once per block — keeps K-loop regs low).
    // C/D layout (16x16 shapes): col = l16 (=n), row = quad*4 + reg (=m).
    const float NEG_LOG2E = -1.4426950408889634f;
    float rowsum[2][4];
    #pragma unroll
    for (int i = 0; i < 2; ++i)
        #pragma unroll
        for (int r = 0; r < 4; ++r) rowsum[i][r] = 0.0f;

    #pragma unroll
    for (int j = 0; j < 8; ++j) {
        int ng = bn * 128 + j * 16 + l16;
        float wj  = w[ng];
        float cjl = NEG_LOG2E * constc[ng];
        #pragma unroll
        for (int i = 0; i < 2; ++i)
            #pragma unroll
            for (int r = 0; r < 4; ++r)
                rowsum[i][r] += exp2f(fmaf(acc[i][j][r], NEG_LOG2E, cjl)) * wj;
    }

    #pragma unroll
    for (int mask = 1; mask < 16; mask <<= 1)
        #pragma unroll
        for (int i = 0; i < 2; ++i)
            #pragma unroll
            for (int r = 0; r < 4; ++r)
                rowsum[i][r] += __shfl_xor(rowsum[i][r], mask, 64);

    if (l16 == 0) {
        #pragma unroll
        for (int i = 0; i < 2; ++i)
            #pragma unroll
            for (int r = 0; r < 4; ++r) {
                int mg = bm * 128 + wave_m + i * 16 + quad * 4 + r;
                atomicAdd(&score[mg], rowsum[i][r]);
            }
    }
}

// ---------------------------------------------------------------------------
// finalize: out[n] = sigmoid(score[n] + b)
// ---------------------------------------------------------------------------
__global__ void finalize(const float* __restrict__ score,
                         const float* __restrict__ b,
                         float* __restrict__ out) {
    int n = blockIdx.x * 256 + threadIdx.x;
    if (n < MDIM) {
        float s = score[n] + b[0];
        out[n] = 1.0f / (1.0f + exp2f(-1.4426950408889634f * s));
    }
}

extern "C" void kernel_launch(void* const* d_in, const int* in_sizes, int n_in,
                              void* d_out, int out_size, void* d_ws, size_t ws_size,
                              hipStream_t stream) {
    const float* x       = (const float*)d_in[0];
    const float* centers = (const float*)d_in[1];
    const float* sigmas  = (const float*)d_in[2];
    const float* w_lin   = (const float*)d_in[3];
    const float* b_lin   = (const float*)d_in[4];
    float* out = (float*)d_out;

    char* ws = (char*)d_ws;
    unsigned char* Ap = (unsigned char*)ws;                       // 4 MB
    unsigned char* Bp = (unsigned char*)(ws + (size_t)MDIM * KB); // 1 MB
    float* cc    = (float*)(ws + (size_t)MDIM * KB + (size_t)CDIM * KB); // 16 KB
    float* score = (float*)((char*)cc + CDIM * sizeof(float));    // 64 KB

    prep<<<dim3(2048 + 512), dim3(256), 0, stream>>>(
        x, centers, sigmas, Ap, Bp, cc, score);
    gemm_fused<<<dim3((CDIM / 128) * (MDIM / 128)), dim3(256), 0, stream>>>(
        Ap, Bp, cc, w_lin, score);
    finalize<<<dim3((MDIM + 255) / 256), dim3(256), 0, stream>>>(score, b_lin, out);
}

// Round 6
// 122.171 us; speedup vs baseline: 2.2733x; 1.0634x over previous
//
#include <hip/hip_runtime.h>
#include <cstdint>
#include <cstddef>

// Problem sizes (fixed by the reference)
#define MDIM 16384   // N_INPUT
#define CDIM 4096    // NUM_CENTERS
#define DDIM 256     // DIM
#define KDIM 512     // folded K elements; fp4 -> 256 bytes per row
#define KB   256     // row bytes (fp4)

typedef float f32x4  __attribute__((ext_vector_type(4)));
typedef int   i32x4v __attribute__((ext_vector_type(4)));
typedef int   i32x8v __attribute__((ext_vector_type(8)));

// e2m1 (OCP MXFP4) quantize, round-to-nearest: grid {0,.5,1,1.5,2,3,4,6}
__device__ __forceinline__ unsigned q4(float v) {
    unsigned s = (__builtin_bit_cast(unsigned, v) >> 31) << 3;
    float a = fabsf(v);
    unsigned c = (unsigned)(a >= 0.25f) + (a >= 0.75f) + (a >= 1.25f)
               + (a >= 1.75f) + (a >= 2.5f) + (a >= 3.5f) + (a >= 5.0f);
    return s | c;
}
__device__ __forceinline__ unsigned pack8(const float* v) {  // 8 vals -> 8 nibbles
    unsigned w = 0;
    #pragma unroll
    for (int i = 0; i < 8; ++i) w |= q4(v[i]) << (4 * i);
    return w;
}

// ---------------------------------------------------------------------------
// prep (fp4): A'[n] = [ x (256 fp4) | x^2/8 (256 fp4) ]       row = 256 B
//             B'[c] = [ -2*c*inv (256 fp4) | inv*8 (256 fp4) ]
//             constc[c] = sum_d c^2*inv (fp32).  Scales undone by MFMA E8M0.
// ---------------------------------------------------------------------------
__global__ __launch_bounds__(256) void prep(
    const float* __restrict__ x, const float* __restrict__ centers,
    const float* __restrict__ sigmas,
    unsigned char* __restrict__ Ap, unsigned char* __restrict__ Bp,
    float* __restrict__ constc, float* __restrict__ score) {
    int b = blockIdx.x, tid = threadIdx.x;
    if (b < 2048) {
        int idx8 = b * 256 + tid;                 // over MDIM*DDIM/8
        int n = idx8 >> 5, d8 = idx8 & 31;
        float v[8], v2[8];
        *(float4*)(v)     = ((const float4*)x)[idx8 * 2];
        *(float4*)(v + 4) = ((const float4*)x)[idx8 * 2 + 1];
        #pragma unroll
        for (int i = 0; i < 8; ++i) v2[i] = v[i] * v[i] * 0.125f;  // x^2/8
        *(unsigned*)(Ap + (size_t)n * KB + d8 * 4)       = pack8(v);
        *(unsigned*)(Ap + (size_t)n * KB + 128 + d8 * 4) = pack8(v2);
        if (idx8 < MDIM) score[idx8] = 0.0f;
    } else {
        int gid8 = (b - 2048) * 256 + tid;        // over CDIM*DDIM/8
        int c = gid8 >> 5, d8 = gid8 & 31;
        float cv[8], sv[8], cr[8], iv[8];
        *(float4*)(cv)     = ((const float4*)centers)[gid8 * 2];
        *(float4*)(cv + 4) = ((const float4*)centers)[gid8 * 2 + 1];
        *(float4*)(sv)     = ((const float4*)sigmas)[gid8 * 2];
        *(float4*)(sv + 4) = ((const float4*)sigmas)[gid8 * 2 + 1];
        float t = 0.0f;
        #pragma unroll
        for (int i = 0; i < 8; ++i) {
            float inv = 1.0f / (2.0f * sv[i] * sv[i]);
            cr[i] = -2.0f * cv[i] * inv;
            iv[i] = inv * 8.0f;                   // inv*8 (undone by 2^-3)
            t += cv[i] * cv[i] * inv;
        }
        *(unsigned*)(Bp + (size_t)c * KB + d8 * 4)       = pack8(cr);
        *(unsigned*)(Bp + (size_t)c * KB + 128 + d8 * 4) = pack8(iv);
        #pragma unroll
        for (int m = 16; m; m >>= 1) t += __shfl_xor(t, m, 64);  // 32-lane groups
        if ((tid & 31) == 0) constc[c] = t;
    }
}

// ---------------------------------------------------------------------------
// Fused MX-fp4 GEMM + exp + weighted C-reduction.  (R20)
// d2 = A' B'^T + constc ; score[m] += sum_n exp(-d2[m][n]) * w[n]
//
// R20 = R16 single-barrier structure (best measured: 45.0 µs), natural 2D
// grid (R19's XCD remap cut FETCH 17->6.3 MB but COST 10 µs -> gemm is
// not BW-bound; remap reverted), with two isolated fixes:
//   1. LDS as two stride-128 [128][128] buffers (3x measured 0 bank
//      conflicts).  R16's [128][256] buffer measured 2.1M conflict-cycles.
//   2. Epilogue constants (w, constc) prefetched into registers BEFORE
//      the barrier — R16 loaded them after the K-loop, fully exposed on
//      every block's tail; now they hide under the same vmcnt drain.
//      acc lives in AGPRs (VGPR_Count 64 measured), so +16 VGPR is free
//      at 3 waves/SIMD.
// Ladder so far: Δtotal == Δgemm (5 rounds); fills+prep+finalize ≈ 74 µs
// fixed.  R17 (persistent 8-tile, 2/CU): -TLP, +16 µs.  R18 (fused
// finalize tail): 5x blowup.  R19 (remap): +10 µs.
// ---------------------------------------------------------------------------
#define AS1 __attribute__((address_space(1)))
#define AS3 __attribute__((address_space(3)))

__global__ __launch_bounds__(256, 3) void gemm_fused(
    const unsigned char* __restrict__ A, const unsigned char* __restrict__ B,
    const float* __restrict__ constc, const float* __restrict__ w,
    float* __restrict__ score) {

    __shared__ unsigned char Bs0[128 * 128];   // K-half 0 (bytes 0..127)
    __shared__ unsigned char Bs1[128 * 128];   // K-half 1 (bytes 128..255)

    const int tid  = threadIdx.x;
    const int wave = tid >> 6;
    const int lane = tid & 63;
    const int quad = lane >> 4;      // 0..3
    const int l16  = lane & 15;

    const int bn = blockIdx.x;       // 0..31   (C blocks of 128)
    const int bm = blockIdx.y;       // 0..127  (M blocks of 128)

    const int wave_m = wave * 32;    // wave's 32 M-rows

    // ---- stage B (conflict-free pattern): slab = 8 rows x 128 B per buffer;
    // lane -> row (lane>>3), chunk (lane&7); source pre-swizzled chunk^row.
    const unsigned char* Bbase = B + (size_t)(bn * 128) * KB;
    {
        const int st_row = lane >> 3;                  // 0..7
        const int st_k   = ((lane & 7) ^ st_row) * 16; // swizzled byte off
        #pragma unroll
        for (int c = 0; c < 4; ++c) {
            int slab = wave * 4 + c;                   // 0..15
            const unsigned char* g0 = Bbase + (size_t)(slab * 8 + st_row) * KB + st_k;
            __builtin_amdgcn_global_load_lds((const AS1 void*)g0,
                (AS3 void*)(Bs0 + slab * 1024), 16, 0, 0);
            const unsigned char* g1 = Bbase + (size_t)(slab * 8 + st_row) * KB + 128 + st_k;
            __builtin_amdgcn_global_load_lds((const AS1 void*)g1,
                (AS3 void*)(Bs1 + slab * 1024), 16, 0, 0);
        }
    }

    // ---- epilogue constants prefetched NOW: latency hides under the drain.
    const float NEG_LOG2E = -1.4426950408889634f;
    float wj[8], cjl[8];
    #pragma unroll
    for (int j = 0; j < 8; ++j) {
        int ng = bn * 128 + j * 16 + l16;
        wj[j]  = w[ng];
        cjl[j] = NEG_LOG2E * constc[ng];
    }

    // ---- A fragments direct global->VGPR (wave-private; L2/L3-served).
    // row = bm*128 + wave_m + i*16 + l16; byte = kh*64 + quad*16.
    const unsigned char* Abase = A + (size_t)(bm * 128 + wave_m) * KB;
    i32x4v af[2][4];
    #pragma unroll
    for (int i = 0; i < 2; ++i)
        #pragma unroll
        for (int kh = 0; kh < 4; ++kh)
            af[i][kh] = *(const i32x4v*)(Abase + (size_t)(i * 16 + l16) * KB
                                         + kh * 64 + quad * 16);

    __syncthreads();   // single drain: B in LDS, af + constants in regs

    f32x4 acc[2][8] = {};
    const int rsw = l16 & 7;
    #pragma unroll
    for (int kh = 0; kh < 4; ++kh) {          // 4 K-windows of 128 elems
        const int sA = (kh & 2) ? 0x82828282 : 0x7F7F7F7F;   // 2^3 : 2^0
        const int sB = (kh & 2) ? 0x7C7C7C7C : 0x7F7F7F7F;   // 2^-3 : 2^0
        const unsigned char* Bbuf = (kh >> 1) ? Bs1 : Bs0;
        const int sl = ((((kh & 1) * 4 + quad) ^ rsw) * 16);
        #pragma unroll
        for (int j = 0; j < 8; ++j) {
            i32x4v lo = *(const i32x4v*)(Bbuf + (j * 16 + l16) * 128 + sl);
            i32x8v bf = __builtin_shufflevector(lo, lo, 0, 1, 2, 3, -1, -1, -1, -1);
            #pragma unroll
            for (int i = 0; i < 2; ++i) {
                i32x8v a8 = __builtin_shufflevector(af[i][kh], af[i][kh],
                                                    0, 1, 2, 3, -1, -1, -1, -1);
                acc[i][j] = __builtin_amdgcn_mfma_scale_f32_16x16x128_f8f6f4(
                    a8, bf, acc[i][j],
                    4 /*cbsz: fp4 e2m1*/, 4 /*blgp: fp4 e2m1*/,
                    0, sA, 0, sB);
            }
        }
    }

    // Epilogue.  C/D layout (16x16): col = l16 (=n), row = quad*4 + reg (=m).
    float rowsum[2][4];
    #pragma unroll
    for (int i = 0; i < 2; ++i)
        #pragma unroll
        for (int r = 0; r < 4; ++r) rowsum[i][r] = 0.0f;

    #pragma unroll
    for (int j = 0; j < 8; ++j) {
        #pragma unroll
        for (int i = 0; i < 2; ++i)
            #pragma unroll
            for (int r = 0; r < 4; ++r)
                rowsum[i][r] += exp2f(fmaf(acc[i][j][r], NEG_LOG2E, cjl[j])) * wj[j];
    }

    #pragma unroll
    for (int mask = 1; mask < 16; mask <<= 1)
        #pragma unroll
        for (int i = 0; i < 2; ++i)
            #pragma unroll
            for (int r = 0; r < 4; ++r)
                rowsum[i][r] += __shfl_xor(rowsum[i][r], mask, 64);

    if (l16 == 0) {
        #pragma unroll
        for (int i = 0; i < 2; ++i)
            #pragma unroll
            for (int r = 0; r < 4; ++r) {
                int mg = bm * 128 + wave_m + i * 16 + quad * 4 + r;
                atomicAdd(&score[mg], rowsum[i][r]);
            }
    }
}

// ---------------------------------------------------------------------------
// finalize: out[n] = sigmoid(score[n] + b)
// ---------------------------------------------------------------------------
__global__ void finalize(const float* __restrict__ score,
                         const float* __restrict__ b,
                         float* __restrict__ out) {
    int n = blockIdx.x * 256 + threadIdx.x;
    if (n < MDIM) {
        float s = score[n] + b[0];
        out[n] = 1.0f / (1.0f + exp2f(-1.4426950408889634f * s));
    }
}

extern "C" void kernel_launch(void* const* d_in, const int* in_sizes, int n_in,
                              void* d_out, int out_size, void* d_ws, size_t ws_size,
                              hipStream_t stream) {
    const float* x       = (const float*)d_in[0];
    const float* centers = (const float*)d_in[1];
    const float* sigmas  = (const float*)d_in[2];
    const float* w_lin   = (const float*)d_in[3];
    const float* b_lin   = (const float*)d_in[4];
    float* out = (float*)d_out;

    char* ws = (char*)d_ws;
    unsigned char* Ap = (unsigned char*)ws;                       // 4 MB
    unsigned char* Bp = (unsigned char*)(ws + (size_t)MDIM * KB); // 1 MB
    float* cc    = (float*)(ws + (size_t)MDIM * KB + (size_t)CDIM * KB); // 16 KB
    float* score = (float*)((char*)cc + CDIM * sizeof(float));    // 64 KB

    prep<<<dim3(2048 + 512), dim3(256), 0, stream>>>(
        x, centers, sigmas, Ap, Bp, cc, score);
    gemm_fused<<<dim3(CDIM / 128, MDIM / 128), dim3(256), 0, stream>>>(
        Ap, Bp, cc, w_lin, score);
    finalize<<<dim3((MDIM + 255) / 256), dim3(256), 0, stream>>>(score, b_lin, out);
}